// Round 1
// baseline (1208.740 us; speedup 1.0000x reference)
//
#include <hip/hip_runtime.h>
#include <hip/hip_bf16.h>
#include <math.h>

// Problem constants
#define BB 16
#define SS 512
#define TT 128
#define EE 256
#define ENC 32
#define DEC 128
#define VOUT 32000

__device__ __forceinline__ float sigmoidf_(float x) { return 1.0f / (1.0f + expf(-x)); }

// ---------------------------------------------------------------------------
// K2: fused source-embedding(+pos-encoding) and input projection for both LSTM
// directions.  Z{f,b}[bs, j] = sum_e src[bs,e] * W{f,b}[e,j] + b{f,b}[j]
// grid: 1024 blocks (8 rows each), 256 threads
// ---------------------------------------------------------------------------
__global__ __launch_bounds__(256) void k_embed_gemm(
    const int* __restrict__ source, const float* __restrict__ src_emb,
    const float* __restrict__ Wf, const float* __restrict__ bf,
    const float* __restrict__ Wb, const float* __restrict__ bb,
    float* __restrict__ Zf, float* __restrict__ Zb)
{
    __shared__ __align__(16) float sSrc[8][EE];
    const int r0 = blockIdx.x * 8;
    const int tid = threadIdx.x;

    // stage 8 src rows: emb*sqrt(E) + positional encoding
    for (int idx = tid; idx < 8 * EE; idx += 256) {
        const int r = idx >> 8, e = idx & 255;
        const int row = r0 + r;
        const int s = row & (SS - 1);
        const int tok = source[row];
        float v = src_emb[(size_t)tok * EE + e] * 16.0f;  // sqrt(256)=16
        const int jh = (e < 128) ? e : (e - 128);
        const float rate = expf(-0.07195578415f * (float)jh);  // ln(10000)/128
        const float ang = (float)s * rate;
        v += (e < 128) ? sinf(ang) : cosf(ang);
        sSrc[r][e] = v;
    }
    __syncthreads();

    const int j = tid & 127;
    const float* W = (tid < 128) ? Wf : Wb;
    const float* bv = (tid < 128) ? bf : bb;
    float* Zo = (tid < 128) ? Zf : Zb;

    float acc[8];
    const float bias = bv[j];
#pragma unroll
    for (int r = 0; r < 8; ++r) acc[r] = bias;

    for (int e = 0; e < EE; e += 4) {
        const float w0 = W[(e + 0) * 128 + j];
        const float w1 = W[(e + 1) * 128 + j];
        const float w2 = W[(e + 2) * 128 + j];
        const float w3 = W[(e + 3) * 128 + j];
#pragma unroll
        for (int r = 0; r < 8; ++r) {
            const float4 x = *(const float4*)&sSrc[r][e];
            acc[r] = fmaf(x.x, w0, acc[r]);
            acc[r] = fmaf(x.y, w1, acc[r]);
            acc[r] = fmaf(x.z, w2, acc[r]);
            acc[r] = fmaf(x.w, w3, acc[r]);
        }
    }
#pragma unroll
    for (int r = 0; r < 8; ++r) Zo[(size_t)(r0 + r) * 128 + j] = acc[r];
}

// ---------------------------------------------------------------------------
// K3: the sequential LSTM scans.  One block per (batch, direction).
// grid: 32 blocks, 128 threads.  Gate order i,f,g,o (Keras).
// enc[b,t,0:32]=forward h, enc[b,t,32:64]=backward h.
// hidden[b,0:32]=h_f(final), hidden[b,32:64]=h_b(final)
// ---------------------------------------------------------------------------
__global__ __launch_bounds__(128) void k_scan(
    const float* __restrict__ Zf, const float* __restrict__ Zb,
    const float* __restrict__ Uf, const float* __restrict__ Ub,
    float* __restrict__ enc, float* __restrict__ hidden)
{
    const int blk = blockIdx.x;
    const int batch = blk >> 1;
    const int dir = blk & 1;
    const float* Z = dir ? Zb : Zf;
    const float* U = dir ? Ub : Uf;
    const int j = threadIdx.x;

    float u[ENC];
#pragma unroll
    for (int k = 0; k < ENC; ++k) u[k] = U[k * 128 + j];  // coalesced

    __shared__ __align__(16) float sh[ENC];
    __shared__ float sc_[ENC];
    __shared__ float sz[128];
    if (j < ENC) { sh[j] = 0.0f; sc_[j] = 0.0f; }
    __syncthreads();

    const float* Zp = Z + (size_t)batch * (SS * 128) + j;
    float zin = Zp[(dir ? (SS - 1) : 0) * 128];

    for (int step = 0; step < SS; ++step) {
        const int t = dir ? (SS - 1 - step) : step;
        float acc0 = zin;
        if (step < SS - 1) {  // prefetch next timestep's precomputed gate input
            const int tn = dir ? (SS - 2 - step) : (step + 1);
            zin = Zp[tn * 128];
        }
        // h(t-1) @ U : 32-long dot, 4 accumulators to shorten the dep chain
        float acc1 = 0.f, acc2 = 0.f, acc3 = 0.f;
        {
            const float4 h0 = *(const float4*)&sh[0];
            const float4 h1 = *(const float4*)&sh[4];
            const float4 h2 = *(const float4*)&sh[8];
            const float4 h3 = *(const float4*)&sh[12];
            const float4 h4 = *(const float4*)&sh[16];
            const float4 h5 = *(const float4*)&sh[20];
            const float4 h6 = *(const float4*)&sh[24];
            const float4 h7 = *(const float4*)&sh[28];
            acc0 = fmaf(h0.x, u[0], acc0);  acc0 = fmaf(h0.y, u[1], acc0);
            acc0 = fmaf(h0.z, u[2], acc0);  acc0 = fmaf(h0.w, u[3], acc0);
            acc1 = fmaf(h1.x, u[4], acc1);  acc1 = fmaf(h1.y, u[5], acc1);
            acc1 = fmaf(h1.z, u[6], acc1);  acc1 = fmaf(h1.w, u[7], acc1);
            acc2 = fmaf(h2.x, u[8], acc2);  acc2 = fmaf(h2.y, u[9], acc2);
            acc2 = fmaf(h2.z, u[10], acc2); acc2 = fmaf(h2.w, u[11], acc2);
            acc3 = fmaf(h3.x, u[12], acc3); acc3 = fmaf(h3.y, u[13], acc3);
            acc3 = fmaf(h3.z, u[14], acc3); acc3 = fmaf(h3.w, u[15], acc3);
            acc0 = fmaf(h4.x, u[16], acc0); acc0 = fmaf(h4.y, u[17], acc0);
            acc0 = fmaf(h4.z, u[18], acc0); acc0 = fmaf(h4.w, u[19], acc0);
            acc1 = fmaf(h5.x, u[20], acc1); acc1 = fmaf(h5.y, u[21], acc1);
            acc1 = fmaf(h5.z, u[22], acc1); acc1 = fmaf(h5.w, u[23], acc1);
            acc2 = fmaf(h6.x, u[24], acc2); acc2 = fmaf(h6.y, u[25], acc2);
            acc2 = fmaf(h6.z, u[26], acc2); acc2 = fmaf(h6.w, u[27], acc2);
            acc3 = fmaf(h7.x, u[28], acc3); acc3 = fmaf(h7.y, u[29], acc3);
            acc3 = fmaf(h7.z, u[30], acc3); acc3 = fmaf(h7.w, u[31], acc3);
        }
        const float zval = (acc0 + acc1) + (acc2 + acc3);
        // activation: j<32 -> i (sig), 32..63 -> f (sig), 64..95 -> g (tanh), 96..127 -> o (sig)
        const float a = (j < 64 || j >= 96) ? sigmoidf_(zval) : tanhf(zval);
        sz[j] = a;
        __syncthreads();
        if (j < ENC) {
            const float c = sz[32 + j] * sc_[j] + sz[j] * sz[64 + j];
            const float h = sz[96 + j] * tanhf(c);
            sc_[j] = c;
            sh[j] = h;
            enc[((size_t)batch * SS + t) * 64 + dir * ENC + j] = h;
            if (step == SS - 1) hidden[batch * 64 + dir * ENC + j] = h;
        }
        __syncthreads();
    }
}

// ---------------------------------------------------------------------------
// K4a: q2[b,d] = hidden[b,:] @ W1[:,d] + b1[d] + b2[d]   (grid 16, 128 thr)
// ---------------------------------------------------------------------------
__global__ __launch_bounds__(128) void k_q(
    const float* __restrict__ hidden, const float* __restrict__ W1,
    const float* __restrict__ b1, const float* __restrict__ b2,
    float* __restrict__ q2)
{
    const int b = blockIdx.x, d = threadIdx.x;
    __shared__ __align__(16) float shid[64];
    if (d < 64) shid[d] = hidden[b * 64 + d];
    __syncthreads();
    float acc = b1[d] + b2[d];
#pragma unroll
    for (int k = 0; k < 64; k += 4) {
        const float4 h4 = *(const float4*)&shid[k];
        acc = fmaf(h4.x, W1[(k + 0) * 128 + d], acc);
        acc = fmaf(h4.y, W1[(k + 1) * 128 + d], acc);
        acc = fmaf(h4.z, W1[(k + 2) * 128 + d], acc);
        acc = fmaf(h4.w, W1[(k + 3) * 128 + d], acc);
    }
    q2[b * 128 + d] = acc;
}

// ---------------------------------------------------------------------------
// K4b: scores[bs] = tanh(q2[b,:] + enc[bs,:]@W2) @ Vw + Vb  (grid 8192, 128 thr)
// ---------------------------------------------------------------------------
__global__ __launch_bounds__(128) void k_score(
    const float* __restrict__ enc, const float* __restrict__ q2,
    const float* __restrict__ W2, const float* __restrict__ Vw,
    const float* __restrict__ Vb, float* __restrict__ scores)
{
    const int bs = blockIdx.x;
    const int b = bs >> 9;
    const int tid = threadIdx.x;
    __shared__ __align__(16) float se[64];
    __shared__ float sred2[2];
    if (tid < 64) se[tid] = enc[(size_t)bs * 64 + tid];
    __syncthreads();
    float acc = q2[b * 128 + tid];
#pragma unroll
    for (int k = 0; k < 64; k += 4) {
        const float4 e4 = *(const float4*)&se[k];
        acc = fmaf(e4.x, W2[(k + 0) * 128 + tid], acc);
        acc = fmaf(e4.y, W2[(k + 1) * 128 + tid], acc);
        acc = fmaf(e4.z, W2[(k + 2) * 128 + tid], acc);
        acc = fmaf(e4.w, W2[(k + 3) * 128 + tid], acc);
    }
    float v = tanhf(acc) * Vw[tid];
#pragma unroll
    for (int off = 32; off > 0; off >>= 1) v += __shfl_down(v, off);
    if ((tid & 63) == 0) sred2[tid >> 6] = v;
    __syncthreads();
    if (tid == 0) scores[bs] = sred2[0] + sred2[1] + Vb[0];
}

// ---------------------------------------------------------------------------
// K4c: softmax over S + context vector.  grid 16 blocks, 512 threads.
// ---------------------------------------------------------------------------
__global__ __launch_bounds__(512) void k_softmax_ctx(
    const float* __restrict__ scores, const float* __restrict__ enc,
    float* __restrict__ ctx)
{
    const int b = blockIdx.x, tid = threadIdx.x;
    __shared__ float sw[SS];
    __shared__ float sred[SS];
    const float sc = scores[b * SS + tid];
    sred[tid] = sc;
    __syncthreads();
    for (int s2 = 256; s2 > 0; s2 >>= 1) {
        if (tid < s2) sred[tid] = fmaxf(sred[tid], sred[tid + s2]);
        __syncthreads();
    }
    const float mx = sred[0];
    __syncthreads();
    const float ex = expf(sc - mx);
    sw[tid] = ex;
    sred[tid] = ex;
    __syncthreads();
    for (int s2 = 256; s2 > 0; s2 >>= 1) {
        if (tid < s2) sred[tid] += sred[tid + s2];
        __syncthreads();
    }
    const float inv = 1.0f / sred[0];
    __syncthreads();
    // weighted sum over S, split into 8 chunks of 64 steps
    const int d = tid & 63, chunk = tid >> 6;
    float acc = 0.0f;
    const int sbeg = chunk * 64;
    for (int s = sbeg; s < sbeg + 64; ++s)
        acc = fmaf(sw[s], enc[((size_t)b * SS + s) * 64 + d], acc);
    sred[tid] = acc * inv;
    __syncthreads();
    if (tid < 64) {
        float t = 0.0f;
#pragma unroll
        for (int c = 0; c < 8; ++c) t += sred[c * 64 + tid];
        ctx[b * 64 + tid] = t;
    }
}

// ---------------------------------------------------------------------------
// K5: decoder gates (forget gate inert since c0=0): Hd[bt,u] =
//   sig(z_o)*tanh(sig(z_i)*tanh(z_g)),  z = [ctx,temb] @ Wd + bd
// grid 256 blocks (8 timesteps each), 384 threads (3 gates x 128 units)
// ---------------------------------------------------------------------------
__global__ __launch_bounds__(384) void k_dec(
    const int* __restrict__ target, const float* __restrict__ tgt_emb,
    const float* __restrict__ ctx, const float* __restrict__ Wd,
    const float* __restrict__ bd, float* __restrict__ Hd)
{
    const int bt0 = blockIdx.x * 8;
    const int tid = threadIdx.x;
    __shared__ __align__(16) float sx[8][320];
    __shared__ float sg[3][8][128];

    for (int idx = tid; idx < 8 * 320; idx += 384) {
        const int r = idx / 320, k = idx % 320;
        const int bt = bt0 + r;
        const int b = bt >> 7;
        float v;
        if (k < 64) v = ctx[b * 64 + k];
        else v = tgt_emb[(size_t)target[bt] * EE + (k - 64)];
        sx[r][k] = v;
    }
    __syncthreads();

    const int g = tid >> 7, u = tid & 127;
    const int col = (g == 0) ? u : ((g == 1) ? (256 + u) : (384 + u));
    float acc[8];
    const float bias = bd[col];
#pragma unroll
    for (int r = 0; r < 8; ++r) acc[r] = bias;

#pragma unroll 2
    for (int k = 0; k < 320; k += 4) {
        const float w0 = Wd[(k + 0) * 512 + col];
        const float w1 = Wd[(k + 1) * 512 + col];
        const float w2 = Wd[(k + 2) * 512 + col];
        const float w3 = Wd[(k + 3) * 512 + col];
#pragma unroll
        for (int r = 0; r < 8; ++r) {
            const float4 x = *(const float4*)&sx[r][k];
            acc[r] = fmaf(x.x, w0, acc[r]);
            acc[r] = fmaf(x.y, w1, acc[r]);
            acc[r] = fmaf(x.z, w2, acc[r]);
            acc[r] = fmaf(x.w, w3, acc[r]);
        }
    }
#pragma unroll
    for (int r = 0; r < 8; ++r) {
        const float a = acc[r];
        sg[g][r][u] = (g == 1) ? tanhf(a) : sigmoidf_(a);
    }
    __syncthreads();
    if (tid < 128) {
#pragma unroll
        for (int r = 0; r < 8; ++r) {
            const float i_ = sg[0][r][u];
            const float g_ = sg[1][r][u];
            const float o_ = sg[2][r][u];
            Hd[(size_t)(bt0 + r) * 128 + u] = o_ * tanhf(i_ * g_);
        }
    }
}

// ---------------------------------------------------------------------------
// K6: output GEMM  C(2048,32000) = Hd(2048,128) @ Wfc(128,32000) + bfc
// fp32 vector-ALU GEMM. Block tile 128x128, 256 threads, 8x8 per thread.
// No LDS: A rows are L1/L2-resident broadcast reads.
// ---------------------------------------------------------------------------
__global__ __launch_bounds__(256) void k_out(
    const float* __restrict__ A, const float* __restrict__ Bw,
    const float* __restrict__ bias, float* __restrict__ C)
{
    const int cb = blockIdx.x * 128;
    const int rb = blockIdx.y * 128;
    const int tid = threadIdx.x;
    const int tx = tid & 15;    // 16 col groups of 4 (+64)
    const int ty = tid >> 4;    // 16 row groups of 8
    const int r0 = rb + ty * 8;
    const int c0 = cb + tx * 4;

    float acc[8][8];
    {
        const float4 bi0 = *(const float4*)&bias[c0];
        const float4 bi1 = *(const float4*)&bias[c0 + 64];
#pragma unroll
        for (int i = 0; i < 8; ++i) {
            acc[i][0] = bi0.x; acc[i][1] = bi0.y; acc[i][2] = bi0.z; acc[i][3] = bi0.w;
            acc[i][4] = bi1.x; acc[i][5] = bi1.y; acc[i][6] = bi1.z; acc[i][7] = bi1.w;
        }
    }

    for (int k = 0; k < 128; k += 4) {
        float4 a4[8];
#pragma unroll
        for (int i = 0; i < 8; ++i)
            a4[i] = *(const float4*)&A[(size_t)(r0 + i) * 128 + k];
#pragma unroll
        for (int c = 0; c < 4; ++c) {
            const float4 b0 = *(const float4*)&Bw[(size_t)(k + c) * VOUT + c0];
            const float4 b1 = *(const float4*)&Bw[(size_t)(k + c) * VOUT + c0 + 64];
#pragma unroll
            for (int i = 0; i < 8; ++i) {
                const float av = (c == 0) ? a4[i].x : (c == 1) ? a4[i].y
                               : (c == 2) ? a4[i].z : a4[i].w;
                acc[i][0] = fmaf(av, b0.x, acc[i][0]);
                acc[i][1] = fmaf(av, b0.y, acc[i][1]);
                acc[i][2] = fmaf(av, b0.z, acc[i][2]);
                acc[i][3] = fmaf(av, b0.w, acc[i][3]);
                acc[i][4] = fmaf(av, b1.x, acc[i][4]);
                acc[i][5] = fmaf(av, b1.y, acc[i][5]);
                acc[i][6] = fmaf(av, b1.z, acc[i][6]);
                acc[i][7] = fmaf(av, b1.w, acc[i][7]);
            }
        }
    }

#pragma unroll
    for (int i = 0; i < 8; ++i) {
        float* Crow = C + (size_t)(r0 + i) * VOUT;
        const float4 o0 = make_float4(acc[i][0], acc[i][1], acc[i][2], acc[i][3]);
        const float4 o1 = make_float4(acc[i][4], acc[i][5], acc[i][6], acc[i][7]);
        *(float4*)(Crow + c0) = o0;
        *(float4*)(Crow + c0 + 64) = o1;
    }
}

// ---------------------------------------------------------------------------
extern "C" void kernel_launch(void* const* d_in, const int* in_sizes, int n_in,
                              void* d_out, int out_size, void* d_ws, size_t ws_size,
                              hipStream_t stream) {
    (void)in_sizes; (void)n_in; (void)out_size; (void)ws_size;
    const int*   source  = (const int*)  d_in[0];
    const int*   target  = (const int*)  d_in[1];
    const float* src_emb = (const float*)d_in[2];
    const float* tgt_emb = (const float*)d_in[3];
    const float* Wf      = (const float*)d_in[4];
    const float* Uf      = (const float*)d_in[5];
    const float* bf      = (const float*)d_in[6];
    const float* Wb      = (const float*)d_in[7];
    const float* Ub      = (const float*)d_in[8];
    const float* bb      = (const float*)d_in[9];
    const float* W1      = (const float*)d_in[10];
    const float* b1      = (const float*)d_in[11];
    const float* W2      = (const float*)d_in[12];
    const float* b2      = (const float*)d_in[13];
    const float* Vw      = (const float*)d_in[14];
    const float* Vb      = (const float*)d_in[15];
    const float* Wd      = (const float*)d_in[16];
    const float* bd      = (const float*)d_in[17];
    const float* Wfc     = (const float*)d_in[18];
    const float* bfc     = (const float*)d_in[19];
    float* out = (float*)d_out;

    // workspace layout (floats)
    float* ws     = (float*)d_ws;
    float* Zf     = ws;                      // 16*512*128 = 1048576
    float* Zb     = Zf + 1048576;            // 1048576
    float* enc    = Zb + 1048576;            // 16*512*64 = 524288
    float* hidden = enc + 524288;            // 16*64 = 1024
    float* q2     = hidden + 1024;           // 16*128 = 2048
    float* scores = q2 + 2048;               // 16*512 = 8192
    float* ctx    = scores + 8192;           // 1024
    float* Hd     = ctx + 1024;              // 2048*128 = 262144

    k_embed_gemm<<<1024, 256, 0, stream>>>(source, src_emb, Wf, bf, Wb, bb, Zf, Zb);
    k_scan<<<32, 128, 0, stream>>>(Zf, Zb, Uf, Ub, enc, hidden);
    k_q<<<16, 128, 0, stream>>>(hidden, W1, b1, b2, q2);
    k_score<<<8192, 128, 0, stream>>>(enc, q2, W2, Vw, Vb, scores);
    k_softmax_ctx<<<16, 512, 0, stream>>>(scores, enc, ctx);
    k_dec<<<256, 384, 0, stream>>>(target, tgt_emb, ctx, Wd, bd, Hd);
    k_out<<<dim3(250, 16), 256, 0, stream>>>(Hd, Wfc, bfc, out);
}

// Round 2
// 751.332 us; speedup vs baseline: 1.6088x; 1.6088x over previous
//
#include <hip/hip_runtime.h>
#include <hip/hip_bf16.h>
#include <math.h>

// Problem constants
#define BB 16
#define SS 512
#define TT 128
#define EE 256
#define ENC 32
#define DEC 128
#define VOUT 32000

typedef _Float16 half8 __attribute__((ext_vector_type(8)));
typedef float floatx4 __attribute__((ext_vector_type(4)));

__device__ __forceinline__ float sigmoidf_(float x) { return 1.0f / (1.0f + expf(-x)); }

// ---------------------------------------------------------------------------
// K2: fused source-embedding(+pos-encoding) and input projection for both LSTM
// directions.  Z{f,b}[bs, j] = sum_e src[bs,e] * W{f,b}[e,j] + b{f,b}[j]
// grid: 1024 blocks (8 rows each), 256 threads
// ---------------------------------------------------------------------------
__global__ __launch_bounds__(256) void k_embed_gemm(
    const int* __restrict__ source, const float* __restrict__ src_emb,
    const float* __restrict__ Wf, const float* __restrict__ bf,
    const float* __restrict__ Wb, const float* __restrict__ bb,
    float* __restrict__ Zf, float* __restrict__ Zb)
{
    __shared__ __align__(16) float sSrc[8][EE];
    const int r0 = blockIdx.x * 8;
    const int tid = threadIdx.x;

    // stage 8 src rows: emb*sqrt(E) + positional encoding
    for (int idx = tid; idx < 8 * EE; idx += 256) {
        const int r = idx >> 8, e = idx & 255;
        const int row = r0 + r;
        const int s = row & (SS - 1);
        const int tok = source[row];
        float v = src_emb[(size_t)tok * EE + e] * 16.0f;  // sqrt(256)=16
        const int jh = (e < 128) ? e : (e - 128);
        const float rate = expf(-0.07195578415f * (float)jh);  // ln(10000)/128
        const float ang = (float)s * rate;
        v += (e < 128) ? sinf(ang) : cosf(ang);
        sSrc[r][e] = v;
    }
    __syncthreads();

    const int j = tid & 127;
    const float* W = (tid < 128) ? Wf : Wb;
    const float* bv = (tid < 128) ? bf : bb;
    float* Zo = (tid < 128) ? Zf : Zb;

    float acc[8];
    const float bias = bv[j];
#pragma unroll
    for (int r = 0; r < 8; ++r) acc[r] = bias;

    for (int e = 0; e < EE; e += 4) {
        const float w0 = W[(e + 0) * 128 + j];
        const float w1 = W[(e + 1) * 128 + j];
        const float w2 = W[(e + 2) * 128 + j];
        const float w3 = W[(e + 3) * 128 + j];
#pragma unroll
        for (int r = 0; r < 8; ++r) {
            const float4 x = *(const float4*)&sSrc[r][e];
            acc[r] = fmaf(x.x, w0, acc[r]);
            acc[r] = fmaf(x.y, w1, acc[r]);
            acc[r] = fmaf(x.z, w2, acc[r]);
            acc[r] = fmaf(x.w, w3, acc[r]);
        }
    }
#pragma unroll
    for (int r = 0; r < 8; ++r) Zo[(size_t)(r0 + r) * 128 + j] = acc[r];
}

// ---------------------------------------------------------------------------
// K3: the sequential LSTM scans.  One block per (batch, direction).
// grid: 32 blocks, 128 threads.  Gate order i,f,g,o (Keras).
// ---------------------------------------------------------------------------
__global__ __launch_bounds__(128) void k_scan(
    const float* __restrict__ Zf, const float* __restrict__ Zb,
    const float* __restrict__ Uf, const float* __restrict__ Ub,
    float* __restrict__ enc, float* __restrict__ hidden)
{
    const int blk = blockIdx.x;
    const int batch = blk >> 1;
    const int dir = blk & 1;
    const float* Z = dir ? Zb : Zf;
    const float* U = dir ? Ub : Uf;
    const int j = threadIdx.x;

    float u[ENC];
#pragma unroll
    for (int k = 0; k < ENC; ++k) u[k] = U[k * 128 + j];  // coalesced

    __shared__ __align__(16) float sh[ENC];
    __shared__ float sc_[ENC];
    __shared__ float sz[128];
    if (j < ENC) { sh[j] = 0.0f; sc_[j] = 0.0f; }
    __syncthreads();

    const float* Zp = Z + (size_t)batch * (SS * 128) + j;
    float zin = Zp[(dir ? (SS - 1) : 0) * 128];

    for (int step = 0; step < SS; ++step) {
        const int t = dir ? (SS - 1 - step) : step;
        float acc0 = zin;
        if (step < SS - 1) {  // prefetch next timestep's precomputed gate input
            const int tn = dir ? (SS - 2 - step) : (step + 1);
            zin = Zp[tn * 128];
        }
        float acc1 = 0.f, acc2 = 0.f, acc3 = 0.f;
        {
            const float4 h0 = *(const float4*)&sh[0];
            const float4 h1 = *(const float4*)&sh[4];
            const float4 h2 = *(const float4*)&sh[8];
            const float4 h3 = *(const float4*)&sh[12];
            const float4 h4 = *(const float4*)&sh[16];
            const float4 h5 = *(const float4*)&sh[20];
            const float4 h6 = *(const float4*)&sh[24];
            const float4 h7 = *(const float4*)&sh[28];
            acc0 = fmaf(h0.x, u[0], acc0);  acc0 = fmaf(h0.y, u[1], acc0);
            acc0 = fmaf(h0.z, u[2], acc0);  acc0 = fmaf(h0.w, u[3], acc0);
            acc1 = fmaf(h1.x, u[4], acc1);  acc1 = fmaf(h1.y, u[5], acc1);
            acc1 = fmaf(h1.z, u[6], acc1);  acc1 = fmaf(h1.w, u[7], acc1);
            acc2 = fmaf(h2.x, u[8], acc2);  acc2 = fmaf(h2.y, u[9], acc2);
            acc2 = fmaf(h2.z, u[10], acc2); acc2 = fmaf(h2.w, u[11], acc2);
            acc3 = fmaf(h3.x, u[12], acc3); acc3 = fmaf(h3.y, u[13], acc3);
            acc3 = fmaf(h3.z, u[14], acc3); acc3 = fmaf(h3.w, u[15], acc3);
            acc0 = fmaf(h4.x, u[16], acc0); acc0 = fmaf(h4.y, u[17], acc0);
            acc0 = fmaf(h4.z, u[18], acc0); acc0 = fmaf(h4.w, u[19], acc0);
            acc1 = fmaf(h5.x, u[20], acc1); acc1 = fmaf(h5.y, u[21], acc1);
            acc1 = fmaf(h5.z, u[22], acc1); acc1 = fmaf(h5.w, u[23], acc1);
            acc2 = fmaf(h6.x, u[24], acc2); acc2 = fmaf(h6.y, u[25], acc2);
            acc2 = fmaf(h6.z, u[26], acc2); acc2 = fmaf(h6.w, u[27], acc2);
            acc3 = fmaf(h7.x, u[28], acc3); acc3 = fmaf(h7.y, u[29], acc3);
            acc3 = fmaf(h7.z, u[30], acc3); acc3 = fmaf(h7.w, u[31], acc3);
        }
        const float zval = (acc0 + acc1) + (acc2 + acc3);
        const float a = (j < 64 || j >= 96) ? sigmoidf_(zval) : tanhf(zval);
        sz[j] = a;
        __syncthreads();
        if (j < ENC) {
            const float c = sz[32 + j] * sc_[j] + sz[j] * sz[64 + j];
            const float h = sz[96 + j] * tanhf(c);
            sc_[j] = c;
            sh[j] = h;
            enc[((size_t)batch * SS + t) * 64 + dir * ENC + j] = h;
            if (step == SS - 1) hidden[batch * 64 + dir * ENC + j] = h;
        }
        __syncthreads();
    }
}

// ---------------------------------------------------------------------------
// K4a: q2[b,d] = hidden[b,:] @ W1[:,d] + b1[d] + b2[d]   (grid 16, 128 thr)
// ---------------------------------------------------------------------------
__global__ __launch_bounds__(128) void k_q(
    const float* __restrict__ hidden, const float* __restrict__ W1,
    const float* __restrict__ b1, const float* __restrict__ b2,
    float* __restrict__ q2)
{
    const int b = blockIdx.x, d = threadIdx.x;
    __shared__ __align__(16) float shid[64];
    if (d < 64) shid[d] = hidden[b * 64 + d];
    __syncthreads();
    float acc = b1[d] + b2[d];
#pragma unroll
    for (int k = 0; k < 64; k += 4) {
        const float4 h4 = *(const float4*)&shid[k];
        acc = fmaf(h4.x, W1[(k + 0) * 128 + d], acc);
        acc = fmaf(h4.y, W1[(k + 1) * 128 + d], acc);
        acc = fmaf(h4.z, W1[(k + 2) * 128 + d], acc);
        acc = fmaf(h4.w, W1[(k + 3) * 128 + d], acc);
    }
    q2[b * 128 + d] = acc;
}

// ---------------------------------------------------------------------------
// K4b: scores[bs] = tanh(q2[b,:] + enc[bs,:]@W2) @ Vw + Vb  (grid 8192, 128 thr)
// ---------------------------------------------------------------------------
__global__ __launch_bounds__(128) void k_score(
    const float* __restrict__ enc, const float* __restrict__ q2,
    const float* __restrict__ W2, const float* __restrict__ Vw,
    const float* __restrict__ Vb, float* __restrict__ scores)
{
    const int bs = blockIdx.x;
    const int b = bs >> 9;
    const int tid = threadIdx.x;
    __shared__ __align__(16) float se[64];
    __shared__ float sred2[2];
    if (tid < 64) se[tid] = enc[(size_t)bs * 64 + tid];
    __syncthreads();
    float acc = q2[b * 128 + tid];
#pragma unroll
    for (int k = 0; k < 64; k += 4) {
        const float4 e4 = *(const float4*)&se[k];
        acc = fmaf(e4.x, W2[(k + 0) * 128 + tid], acc);
        acc = fmaf(e4.y, W2[(k + 1) * 128 + tid], acc);
        acc = fmaf(e4.z, W2[(k + 2) * 128 + tid], acc);
        acc = fmaf(e4.w, W2[(k + 3) * 128 + tid], acc);
    }
    float v = tanhf(acc) * Vw[tid];
#pragma unroll
    for (int off = 32; off > 0; off >>= 1) v += __shfl_down(v, off);
    if ((tid & 63) == 0) sred2[tid >> 6] = v;
    __syncthreads();
    if (tid == 0) scores[bs] = sred2[0] + sred2[1] + Vb[0];
}

// ---------------------------------------------------------------------------
// K4c: softmax over S + context vector.  grid 16 blocks, 512 threads.
// ---------------------------------------------------------------------------
__global__ __launch_bounds__(512) void k_softmax_ctx(
    const float* __restrict__ scores, const float* __restrict__ enc,
    float* __restrict__ ctx)
{
    const int b = blockIdx.x, tid = threadIdx.x;
    __shared__ float sw[SS];
    __shared__ float sred[SS];
    const float sc = scores[b * SS + tid];
    sred[tid] = sc;
    __syncthreads();
    for (int s2 = 256; s2 > 0; s2 >>= 1) {
        if (tid < s2) sred[tid] = fmaxf(sred[tid], sred[tid + s2]);
        __syncthreads();
    }
    const float mx = sred[0];
    __syncthreads();
    const float ex = expf(sc - mx);
    sw[tid] = ex;
    sred[tid] = ex;
    __syncthreads();
    for (int s2 = 256; s2 > 0; s2 >>= 1) {
        if (tid < s2) sred[tid] += sred[tid + s2];
        __syncthreads();
    }
    const float inv = 1.0f / sred[0];
    __syncthreads();
    const int d = tid & 63, chunk = tid >> 6;
    float acc = 0.0f;
    const int sbeg = chunk * 64;
    for (int s = sbeg; s < sbeg + 64; ++s)
        acc = fmaf(sw[s], enc[((size_t)b * SS + s) * 64 + d], acc);
    sred[tid] = acc * inv;
    __syncthreads();
    if (tid < 64) {
        float t = 0.0f;
#pragma unroll
        for (int c = 0; c < 8; ++c) t += sred[c * 64 + tid];
        ctx[b * 64 + tid] = t;
    }
}

// ---------------------------------------------------------------------------
// K5: decoder gates (forget gate inert since c0=0): Ah[bt,u] =
//   fp16( sig(z_o)*tanh(sig(z_i)*tanh(z_g)) ),  z = [ctx,temb] @ Wd + bd
// grid 256 blocks (8 timesteps each), 384 threads (3 gates x 128 units)
// ---------------------------------------------------------------------------
__global__ __launch_bounds__(384) void k_dec(
    const int* __restrict__ target, const float* __restrict__ tgt_emb,
    const float* __restrict__ ctx, const float* __restrict__ Wd,
    const float* __restrict__ bd, unsigned short* __restrict__ Ah)
{
    const int bt0 = blockIdx.x * 8;
    const int tid = threadIdx.x;
    __shared__ __align__(16) float sx[8][320];
    __shared__ float sg[3][8][128];

    for (int idx = tid; idx < 8 * 320; idx += 384) {
        const int r = idx / 320, k = idx % 320;
        const int bt = bt0 + r;
        const int b = bt >> 7;
        float v;
        if (k < 64) v = ctx[b * 64 + k];
        else v = tgt_emb[(size_t)target[bt] * EE + (k - 64)];
        sx[r][k] = v;
    }
    __syncthreads();

    const int g = tid >> 7, u = tid & 127;
    const int col = (g == 0) ? u : ((g == 1) ? (256 + u) : (384 + u));
    float acc[8];
    const float bias = bd[col];
#pragma unroll
    for (int r = 0; r < 8; ++r) acc[r] = bias;

#pragma unroll 2
    for (int k = 0; k < 320; k += 4) {
        const float w0 = Wd[(k + 0) * 512 + col];
        const float w1 = Wd[(k + 1) * 512 + col];
        const float w2 = Wd[(k + 2) * 512 + col];
        const float w3 = Wd[(k + 3) * 512 + col];
#pragma unroll
        for (int r = 0; r < 8; ++r) {
            const float4 x = *(const float4*)&sx[r][k];
            acc[r] = fmaf(x.x, w0, acc[r]);
            acc[r] = fmaf(x.y, w1, acc[r]);
            acc[r] = fmaf(x.z, w2, acc[r]);
            acc[r] = fmaf(x.w, w3, acc[r]);
        }
    }
#pragma unroll
    for (int r = 0; r < 8; ++r) {
        const float a = acc[r];
        sg[g][r][u] = (g == 1) ? tanhf(a) : sigmoidf_(a);
    }
    __syncthreads();
    if (tid < 128) {
#pragma unroll
        for (int r = 0; r < 8; ++r) {
            const float i_ = sg[0][r][u];
            const float g_ = sg[1][r][u];
            const float o_ = sg[2][r][u];
            const float h = o_ * tanhf(i_ * g_);
            Ah[(size_t)(bt0 + r) * 128 + u] =
                __builtin_bit_cast(unsigned short, (_Float16)h);
        }
    }
}

// ---------------------------------------------------------------------------
// K6a: transpose + fp16-convert Wfc (128 x 32000, N-contig)
//      -> Bt (32000 x 128 fp16, K-contig).  grid 500 blocks, 256 threads.
// ---------------------------------------------------------------------------
__global__ __launch_bounds__(256) void k_cvtB(
    const float* __restrict__ Wfc, unsigned short* __restrict__ Bt)
{
    __shared__ __align__(16) unsigned short sH[64][136];  // pad: row stride 272B (16B-aligned, odd*16)
    const int n0 = blockIdx.x * 64;
    const int tid = threadIdx.x;
    const int kk = tid >> 4;       // 0..15
    const int n4 = tid & 15;       // 0..15 (covers 64 cols as float4)

#pragma unroll
    for (int p = 0; p < 8; ++p) {
        const int k = p * 16 + kk;
        const float4 v = *(const float4*)&Wfc[(size_t)k * VOUT + n0 + n4 * 4];
        sH[n4 * 4 + 0][k] = __builtin_bit_cast(unsigned short, (_Float16)v.x);
        sH[n4 * 4 + 1][k] = __builtin_bit_cast(unsigned short, (_Float16)v.y);
        sH[n4 * 4 + 2][k] = __builtin_bit_cast(unsigned short, (_Float16)v.z);
        sH[n4 * 4 + 3][k] = __builtin_bit_cast(unsigned short, (_Float16)v.w);
    }
    __syncthreads();

    const int r0 = tid >> 4;           // 16 rows per pass
    const int l8 = (tid & 15) * 8;     // 8 ushorts = 16B per lane
#pragma unroll
    for (int p = 0; p < 4; ++p) {
        const int r = p * 16 + r0;
        *(uint4*)&Bt[(size_t)(n0 + r) * 128 + l8] = *(const uint4*)&sH[r][l8];
    }
}

// ---------------------------------------------------------------------------
// K6b: output GEMM  C(2048,32000) = Ah(2048,128) @ Bt^T + bfc, f16 MFMA.
// Block tile 128x128, 4 waves (2x2), each wave 64x64 = 4x4 tiles of 16x16.
// Fragments loaded directly from global (A L1-resident, B L2/LLC-resident).
// A-frag: A[m=lane&15][k=quad*8+j]; B-frag: Bt[n=lane&15][k=quad*8+j];
// C/D:    col=lane&15, row=quad*4+reg   (verified gfx950 layouts)
// ---------------------------------------------------------------------------
__global__ __launch_bounds__(256) void k_out_f16(
    const unsigned short* __restrict__ Ah,   // 2048 x 128 fp16
    const unsigned short* __restrict__ Bt,   // 32000 x 128 fp16
    const float* __restrict__ bias, float* __restrict__ C)
{
    const int tid  = threadIdx.x;
    const int wave = tid >> 6;
    const int lane = tid & 63;
    const int wm = wave >> 1, wn = wave & 1;
    const int rb = blockIdx.y * 128 + wm * 64;
    const int cb = blockIdx.x * 128 + wn * 64;
    const int lm = lane & 15;
    const int quad = lane >> 4;

    floatx4 acc[4][4];
#pragma unroll
    for (int nt = 0; nt < 4; ++nt) {
        const float bv = bias[cb + nt * 16 + lm];
#pragma unroll
        for (int mt = 0; mt < 4; ++mt)
            acc[mt][nt] = (floatx4){bv, bv, bv, bv};
    }

    const unsigned short* pA = Ah + (size_t)(rb + lm) * 128 + quad * 8;
    const unsigned short* pB = Bt + (size_t)(cb + lm) * 128 + quad * 8;

#pragma unroll
    for (int kc = 0; kc < 128; kc += 32) {
        half8 af[4], bfr[4];
#pragma unroll
        for (int mt = 0; mt < 4; ++mt)
            af[mt] = *(const half8*)(pA + mt * (16 * 128) + kc);
#pragma unroll
        for (int nt = 0; nt < 4; ++nt)
            bfr[nt] = *(const half8*)(pB + nt * (16 * 128) + kc);
#pragma unroll
        for (int mt = 0; mt < 4; ++mt)
#pragma unroll
            for (int nt = 0; nt < 4; ++nt)
                acc[mt][nt] = __builtin_amdgcn_mfma_f32_16x16x32_f16(
                    af[mt], bfr[nt], acc[mt][nt], 0, 0, 0);
    }

#pragma unroll
    for (int mt = 0; mt < 4; ++mt) {
        const int r0 = rb + mt * 16 + quad * 4;
#pragma unroll
        for (int nt = 0; nt < 4; ++nt) {
            const int col = cb + nt * 16 + lm;
            float* Cp = C + (size_t)r0 * VOUT + col;
#pragma unroll
            for (int r = 0; r < 4; ++r)
                Cp[(size_t)r * VOUT] = acc[mt][nt][r];
        }
    }
}

// ---------------------------------------------------------------------------
extern "C" void kernel_launch(void* const* d_in, const int* in_sizes, int n_in,
                              void* d_out, int out_size, void* d_ws, size_t ws_size,
                              hipStream_t stream) {
    (void)in_sizes; (void)n_in; (void)out_size; (void)ws_size;
    const int*   source  = (const int*)  d_in[0];
    const int*   target  = (const int*)  d_in[1];
    const float* src_emb = (const float*)d_in[2];
    const float* tgt_emb = (const float*)d_in[3];
    const float* Wf      = (const float*)d_in[4];
    const float* Uf      = (const float*)d_in[5];
    const float* bf      = (const float*)d_in[6];
    const float* Wb      = (const float*)d_in[7];
    const float* Ub      = (const float*)d_in[8];
    const float* bb      = (const float*)d_in[9];
    const float* W1      = (const float*)d_in[10];
    const float* b1      = (const float*)d_in[11];
    const float* W2      = (const float*)d_in[12];
    const float* b2      = (const float*)d_in[13];
    const float* Vw      = (const float*)d_in[14];
    const float* Vb      = (const float*)d_in[15];
    const float* Wd      = (const float*)d_in[16];
    const float* bd      = (const float*)d_in[17];
    const float* Wfc     = (const float*)d_in[18];
    const float* bfc     = (const float*)d_in[19];
    float* out = (float*)d_out;

    // workspace layout (float offsets)
    float* ws     = (float*)d_ws;
    float* Zf     = ws;                      // 1048576 f (dead after k_scan)
    float* Zb     = Zf + 1048576;            // 1048576 f (dead after k_scan)
    float* enc    = Zb + 1048576;            // 524288 f
    float* hidden = enc + 524288;            // 1024 f
    float* q2     = hidden + 1024;           // 2048 f
    float* scores = q2 + 2048;               // 8192 f
    float* ctx    = scores + 8192;           // 1024 f
    unsigned short* Ah = (unsigned short*)(ctx + 1024);  // 2048*128 fp16 = 512 KB
    // Bt aliases the dead Zf/Zb region: 32000*128*2B = 8.192 MB <= 8.389 MB
    unsigned short* Bt = (unsigned short*)Zf;

    k_embed_gemm<<<1024, 256, 0, stream>>>(source, src_emb, Wf, bf, Wb, bb, Zf, Zb);
    k_scan<<<32, 128, 0, stream>>>(Zf, Zb, Uf, Ub, enc, hidden);
    k_q<<<16, 128, 0, stream>>>(hidden, W1, b1, b2, q2);
    k_score<<<8192, 128, 0, stream>>>(enc, q2, W2, Vw, Vb, scores);
    k_softmax_ctx<<<16, 512, 0, stream>>>(scores, enc, ctx);
    k_cvtB<<<500, 256, 0, stream>>>(Wfc, Bt);   // after k_scan: Zf/Zb dead
    k_dec<<<256, 384, 0, stream>>>(target, tgt_emb, ctx, Wd, bd, Ah);
    k_out_f16<<<dim3(250, 16), 256, 0, stream>>>(Ah, Bt, bfc, out);
}

// Round 3
// 638.999 us; speedup vs baseline: 1.8916x; 1.1758x over previous
//
#include <hip/hip_runtime.h>
#include <hip/hip_bf16.h>
#include <math.h>

// Problem constants
#define BB 16
#define SS 512
#define TT 128
#define EE 256
#define ENC 32
#define DEC 128
#define VOUT 32000

typedef _Float16 half8 __attribute__((ext_vector_type(8)));
typedef float floatx4 __attribute__((ext_vector_type(4)));

__device__ __forceinline__ float sigmoidf_(float x) { return 1.0f / (1.0f + expf(-x)); }
__device__ __forceinline__ float rcpf_(float x) { return __builtin_amdgcn_rcpf(x); }

// ---------------------------------------------------------------------------
// K2: fused source-embedding(+pos-encoding) and input projection for both LSTM
// directions.  Z{f,b}[bs, j] = sum_e src[bs,e] * W{f,b}[e,j] + b{f,b}[j]
// grid: 1024 blocks (8 rows each), 256 threads
// ---------------------------------------------------------------------------
__global__ __launch_bounds__(256) void k_embed_gemm(
    const int* __restrict__ source, const float* __restrict__ src_emb,
    const float* __restrict__ Wf, const float* __restrict__ bf,
    const float* __restrict__ Wb, const float* __restrict__ bb,
    float* __restrict__ Zf, float* __restrict__ Zb)
{
    __shared__ __align__(16) float sSrc[8][EE];
    const int r0 = blockIdx.x * 8;
    const int tid = threadIdx.x;

    // stage 8 src rows: emb*sqrt(E) + positional encoding
    for (int idx = tid; idx < 8 * EE; idx += 256) {
        const int r = idx >> 8, e = idx & 255;
        const int row = r0 + r;
        const int s = row & (SS - 1);
        const int tok = source[row];
        float v = src_emb[(size_t)tok * EE + e] * 16.0f;  // sqrt(256)=16
        const int jh = (e < 128) ? e : (e - 128);
        const float rate = expf(-0.07195578415f * (float)jh);  // ln(10000)/128
        const float ang = (float)s * rate;
        v += (e < 128) ? sinf(ang) : cosf(ang);
        sSrc[r][e] = v;
    }
    __syncthreads();

    const int j = tid & 127;
    const float* W = (tid < 128) ? Wf : Wb;
    const float* bv = (tid < 128) ? bf : bb;
    float* Zo = (tid < 128) ? Zf : Zb;

    float acc[8];
    const float bias = bv[j];
#pragma unroll
    for (int r = 0; r < 8; ++r) acc[r] = bias;

    for (int e = 0; e < EE; e += 4) {
        const float w0 = W[(e + 0) * 128 + j];
        const float w1 = W[(e + 1) * 128 + j];
        const float w2 = W[(e + 2) * 128 + j];
        const float w3 = W[(e + 3) * 128 + j];
#pragma unroll
        for (int r = 0; r < 8; ++r) {
            const float4 x = *(const float4*)&sSrc[r][e];
            acc[r] = fmaf(x.x, w0, acc[r]);
            acc[r] = fmaf(x.y, w1, acc[r]);
            acc[r] = fmaf(x.z, w2, acc[r]);
            acc[r] = fmaf(x.w, w3, acc[r]);
        }
    }
#pragma unroll
    for (int r = 0; r < 8; ++r) Zo[(size_t)(r0 + r) * 128 + j] = acc[r];
}

// ---------------------------------------------------------------------------
// K3: wave-level LSTM scan.  One 64-lane wave per (batch, direction); no LDS,
// no barriers.  lane = (half, u): half0 computes gates i,f of unit u; half1
// computes g,o.  h lives in lanes 0..31; broadcast via v_readlane (SGPR);
// cross-half combine via two __shfl_xor(.,32).
// grid: 32 blocks, 64 threads.
// ---------------------------------------------------------------------------
__global__ __launch_bounds__(64) void k_scan(
    const float* __restrict__ Zf, const float* __restrict__ Zb,
    const float* __restrict__ Uf, const float* __restrict__ Ub,
    float* __restrict__ enc, float* __restrict__ hidden)
{
    const int blk = blockIdx.x;
    const int batch = blk >> 1;
    const int dir = blk & 1;
    const float* __restrict__ Z = dir ? Zb : Zf;
    const float* __restrict__ U = dir ? Ub : Uf;
    const int lane = threadIdx.x;
    const int u = lane & 31;
    const int half = lane >> 5;
    const int colA = half * 64 + u;        // half0: i, half1: g
    const int colB = half * 64 + 32 + u;   // half0: f, half1: o

    float uA[ENC], uB[ENC];
#pragma unroll
    for (int k = 0; k < ENC; ++k) {
        uA[k] = U[k * 128 + colA];
        uB[k] = U[k * 128 + colB];
    }

    const float* __restrict__ Zrow = Z + (size_t)batch * (SS * 128);
    const int dt = dir ? -1 : 1;
    int t = dir ? (SS - 1) : 0;
    float zA = Zrow[t * 128 + colA];
    float zB = Zrow[t * 128 + colB];

    const float m = half ? 2.0f : 1.0f;    // half1's gate-A is tanh = 2*sig(2x)-1
    const float madd = 1.0f - m;

    float h = 0.0f, c = 0.0f;

    for (int step = 0; step < SS; ++step) {
        float accA0 = zA, accA1 = 0.f, accA2 = 0.f, accA3 = 0.f;
        float accB0 = zB, accB1 = 0.f, accB2 = 0.f, accB3 = 0.f;
        if (step < SS - 1) {               // prefetch next timestep's Z
            const int tn = t + dt;
            zA = Zrow[tn * 128 + colA];
            zB = Zrow[tn * 128 + colB];
        }
        // h(t-1) @ U: broadcast h from lanes 0..31 via readlane (SGPR operand)
#pragma unroll
        for (int k = 0; k < ENC; k += 4) {
            const float h0 = __builtin_bit_cast(float,
                __builtin_amdgcn_readlane(__builtin_bit_cast(int, h), k + 0));
            const float h1 = __builtin_bit_cast(float,
                __builtin_amdgcn_readlane(__builtin_bit_cast(int, h), k + 1));
            const float h2 = __builtin_bit_cast(float,
                __builtin_amdgcn_readlane(__builtin_bit_cast(int, h), k + 2));
            const float h3 = __builtin_bit_cast(float,
                __builtin_amdgcn_readlane(__builtin_bit_cast(int, h), k + 3));
            accA0 = fmaf(h0, uA[k + 0], accA0);
            accB0 = fmaf(h0, uB[k + 0], accB0);
            accA1 = fmaf(h1, uA[k + 1], accA1);
            accB1 = fmaf(h1, uB[k + 1], accB1);
            accA2 = fmaf(h2, uA[k + 2], accA2);
            accB2 = fmaf(h2, uB[k + 2], accB2);
            accA3 = fmaf(h3, uA[k + 3], accA3);
            accB3 = fmaf(h3, uB[k + 3], accB3);
        }
        const float zAv = (accA0 + accA1) + (accA2 + accA3);
        const float zBv = (accB0 + accB1) + (accB2 + accB3);

        // branch-free activations: half0 a1=sig(zA), half1 a1=tanh(zA); a2=sig(zB)
        const float s1 = rcpf_(1.0f + expf(-m * zAv));
        const float a1 = fmaf(s1, m, madd);
        const float a2 = rcpf_(1.0f + expf(-zBv));

        // cross-half exchange: half0 receives (tanh_g, sig_o) from half1
        const float t1 = __shfl_xor(a1, 32);
        const float t2 = __shfl_xor(a2, 32);

        // half0: c = sig_f*c + sig_i*tanh_g ; h = sig_o*tanh(c)
        c = fmaf(a2, c, a1 * t1);
        const float e2 = expf(-2.0f * c);
        const float tc = (1.0f - e2) * rcpf_(1.0f + e2);
        h = t2 * tc;                       // valid in lanes 0..31 only

        if (half == 0)
            enc[((size_t)batch * SS + t) * 64 + dir * ENC + u] = h;
        t += dt;
    }
    if (half == 0)
        hidden[batch * 64 + dir * ENC + u] = h;
}

// ---------------------------------------------------------------------------
// K4a: q2[b,d] = hidden[b,:] @ W1[:,d] + b1[d] + b2[d]   (grid 16, 128 thr)
// ---------------------------------------------------------------------------
__global__ __launch_bounds__(128) void k_q(
    const float* __restrict__ hidden, const float* __restrict__ W1,
    const float* __restrict__ b1, const float* __restrict__ b2,
    float* __restrict__ q2)
{
    const int b = blockIdx.x, d = threadIdx.x;
    __shared__ __align__(16) float shid[64];
    if (d < 64) shid[d] = hidden[b * 64 + d];
    __syncthreads();
    float acc = b1[d] + b2[d];
#pragma unroll
    for (int k = 0; k < 64; k += 4) {
        const float4 h4 = *(const float4*)&shid[k];
        acc = fmaf(h4.x, W1[(k + 0) * 128 + d], acc);
        acc = fmaf(h4.y, W1[(k + 1) * 128 + d], acc);
        acc = fmaf(h4.z, W1[(k + 2) * 128 + d], acc);
        acc = fmaf(h4.w, W1[(k + 3) * 128 + d], acc);
    }
    q2[b * 128 + d] = acc;
}

// ---------------------------------------------------------------------------
// K4b: scores[bs] = tanh(q2[b,:] + enc[bs,:]@W2) @ Vw + Vb  (grid 8192, 128 thr)
// ---------------------------------------------------------------------------
__global__ __launch_bounds__(128) void k_score(
    const float* __restrict__ enc, const float* __restrict__ q2,
    const float* __restrict__ W2, const float* __restrict__ Vw,
    const float* __restrict__ Vb, float* __restrict__ scores)
{
    const int bs = blockIdx.x;
    const int b = bs >> 9;
    const int tid = threadIdx.x;
    __shared__ __align__(16) float se[64];
    __shared__ float sred2[2];
    if (tid < 64) se[tid] = enc[(size_t)bs * 64 + tid];
    __syncthreads();
    float acc = q2[b * 128 + tid];
#pragma unroll
    for (int k = 0; k < 64; k += 4) {
        const float4 e4 = *(const float4*)&se[k];
        acc = fmaf(e4.x, W2[(k + 0) * 128 + tid], acc);
        acc = fmaf(e4.y, W2[(k + 1) * 128 + tid], acc);
        acc = fmaf(e4.z, W2[(k + 2) * 128 + tid], acc);
        acc = fmaf(e4.w, W2[(k + 3) * 128 + tid], acc);
    }
    float v = tanhf(acc) * Vw[tid];
#pragma unroll
    for (int off = 32; off > 0; off >>= 1) v += __shfl_down(v, off);
    if ((tid & 63) == 0) sred2[tid >> 6] = v;
    __syncthreads();
    if (tid == 0) scores[bs] = sred2[0] + sred2[1] + Vb[0];
}

// ---------------------------------------------------------------------------
// K4c: softmax over S + context vector.  grid 16 blocks, 512 threads.
// ---------------------------------------------------------------------------
__global__ __launch_bounds__(512) void k_softmax_ctx(
    const float* __restrict__ scores, const float* __restrict__ enc,
    float* __restrict__ ctx)
{
    const int b = blockIdx.x, tid = threadIdx.x;
    __shared__ float sw[SS];
    __shared__ float sred[SS];
    const float sc = scores[b * SS + tid];
    sred[tid] = sc;
    __syncthreads();
    for (int s2 = 256; s2 > 0; s2 >>= 1) {
        if (tid < s2) sred[tid] = fmaxf(sred[tid], sred[tid + s2]);
        __syncthreads();
    }
    const float mx = sred[0];
    __syncthreads();
    const float ex = expf(sc - mx);
    sw[tid] = ex;
    sred[tid] = ex;
    __syncthreads();
    for (int s2 = 256; s2 > 0; s2 >>= 1) {
        if (tid < s2) sred[tid] += sred[tid + s2];
        __syncthreads();
    }
    const float inv = 1.0f / sred[0];
    __syncthreads();
    const int d = tid & 63, chunk = tid >> 6;
    float acc = 0.0f;
    const int sbeg = chunk * 64;
    for (int s = sbeg; s < sbeg + 64; ++s)
        acc = fmaf(sw[s], enc[((size_t)b * SS + s) * 64 + d], acc);
    sred[tid] = acc * inv;
    __syncthreads();
    if (tid < 64) {
        float t = 0.0f;
#pragma unroll
        for (int c = 0; c < 8; ++c) t += sred[c * 64 + tid];
        ctx[b * 64 + tid] = t;
    }
}

// ---------------------------------------------------------------------------
// K5: decoder gates (forget gate inert since c0=0): Ah[bt,u] =
//   fp16( sig(z_o)*tanh(sig(z_i)*tanh(z_g)) ),  z = [ctx,temb] @ Wd + bd
// grid 256 blocks (8 timesteps each), 384 threads (3 gates x 128 units)
// ---------------------------------------------------------------------------
__global__ __launch_bounds__(384) void k_dec(
    const int* __restrict__ target, const float* __restrict__ tgt_emb,
    const float* __restrict__ ctx, const float* __restrict__ Wd,
    const float* __restrict__ bd, unsigned short* __restrict__ Ah)
{
    const int bt0 = blockIdx.x * 8;
    const int tid = threadIdx.x;
    __shared__ __align__(16) float sx[8][320];
    __shared__ float sg[3][8][128];

    for (int idx = tid; idx < 8 * 320; idx += 384) {
        const int r = idx / 320, k = idx % 320;
        const int bt = bt0 + r;
        const int b = bt >> 7;
        float v;
        if (k < 64) v = ctx[b * 64 + k];
        else v = tgt_emb[(size_t)target[bt] * EE + (k - 64)];
        sx[r][k] = v;
    }
    __syncthreads();

    const int g = tid >> 7, u = tid & 127;
    const int col = (g == 0) ? u : ((g == 1) ? (256 + u) : (384 + u));
    float acc[8];
    const float bias = bd[col];
#pragma unroll
    for (int r = 0; r < 8; ++r) acc[r] = bias;

#pragma unroll 2
    for (int k = 0; k < 320; k += 4) {
        const float w0 = Wd[(k + 0) * 512 + col];
        const float w1 = Wd[(k + 1) * 512 + col];
        const float w2 = Wd[(k + 2) * 512 + col];
        const float w3 = Wd[(k + 3) * 512 + col];
#pragma unroll
        for (int r = 0; r < 8; ++r) {
            const float4 x = *(const float4*)&sx[r][k];
            acc[r] = fmaf(x.x, w0, acc[r]);
            acc[r] = fmaf(x.y, w1, acc[r]);
            acc[r] = fmaf(x.z, w2, acc[r]);
            acc[r] = fmaf(x.w, w3, acc[r]);
        }
    }
#pragma unroll
    for (int r = 0; r < 8; ++r) {
        const float a = acc[r];
        sg[g][r][u] = (g == 1) ? tanhf(a) : sigmoidf_(a);
    }
    __syncthreads();
    if (tid < 128) {
#pragma unroll
        for (int r = 0; r < 8; ++r) {
            const float i_ = sg[0][r][u];
            const float g_ = sg[1][r][u];
            const float o_ = sg[2][r][u];
            const float h = o_ * tanhf(i_ * g_);
            Ah[(size_t)(bt0 + r) * 128 + u] =
                __builtin_bit_cast(unsigned short, (_Float16)h);
        }
    }
}

// ---------------------------------------------------------------------------
// K6a: transpose + fp16-convert Wfc (128 x 32000, N-contig)
//      -> Bt (32000 x 128 fp16, K-contig).  grid 500 blocks, 256 threads.
// ---------------------------------------------------------------------------
__global__ __launch_bounds__(256) void k_cvtB(
    const float* __restrict__ Wfc, unsigned short* __restrict__ Bt)
{
    __shared__ __align__(16) unsigned short sH[64][136];
    const int n0 = blockIdx.x * 64;
    const int tid = threadIdx.x;
    const int kk = tid >> 4;       // 0..15
    const int n4 = tid & 15;       // 0..15

#pragma unroll
    for (int p = 0; p < 8; ++p) {
        const int k = p * 16 + kk;
        const float4 v = *(const float4*)&Wfc[(size_t)k * VOUT + n0 + n4 * 4];
        sH[n4 * 4 + 0][k] = __builtin_bit_cast(unsigned short, (_Float16)v.x);
        sH[n4 * 4 + 1][k] = __builtin_bit_cast(unsigned short, (_Float16)v.y);
        sH[n4 * 4 + 2][k] = __builtin_bit_cast(unsigned short, (_Float16)v.z);
        sH[n4 * 4 + 3][k] = __builtin_bit_cast(unsigned short, (_Float16)v.w);
    }
    __syncthreads();

    const int r0 = tid >> 4;
    const int l8 = (tid & 15) * 8;
#pragma unroll
    for (int p = 0; p < 4; ++p) {
        const int r = p * 16 + r0;
        *(uint4*)&Bt[(size_t)(n0 + r) * 128 + l8] = *(const uint4*)&sH[r][l8];
    }
}

// ---------------------------------------------------------------------------
// K6b: output GEMM  C(2048,32000) = Ah(2048,128) @ Bt^T + bfc, f16 MFMA.
// Block tile 128x128, 4 waves (2x2), each wave 64x64 = 4x4 tiles of 16x16.
// ---------------------------------------------------------------------------
__global__ __launch_bounds__(256) void k_out_f16(
    const unsigned short* __restrict__ Ah,   // 2048 x 128 fp16
    const unsigned short* __restrict__ Bt,   // 32000 x 128 fp16
    const float* __restrict__ bias, float* __restrict__ C)
{
    const int tid  = threadIdx.x;
    const int wave = tid >> 6;
    const int lane = tid & 63;
    const int wm = wave >> 1, wn = wave & 1;
    const int rb = blockIdx.y * 128 + wm * 64;
    const int cb = blockIdx.x * 128 + wn * 64;
    const int lm = lane & 15;
    const int quad = lane >> 4;

    floatx4 acc[4][4];
#pragma unroll
    for (int nt = 0; nt < 4; ++nt) {
        const float bv = bias[cb + nt * 16 + lm];
#pragma unroll
        for (int mt = 0; mt < 4; ++mt)
            acc[mt][nt] = (floatx4){bv, bv, bv, bv};
    }

    const unsigned short* pA = Ah + (size_t)(rb + lm) * 128 + quad * 8;
    const unsigned short* pB = Bt + (size_t)(cb + lm) * 128 + quad * 8;

#pragma unroll
    for (int kc = 0; kc < 128; kc += 32) {
        half8 af[4], bfr[4];
#pragma unroll
        for (int mt = 0; mt < 4; ++mt)
            af[mt] = *(const half8*)(pA + mt * (16 * 128) + kc);
#pragma unroll
        for (int nt = 0; nt < 4; ++nt)
            bfr[nt] = *(const half8*)(pB + nt * (16 * 128) + kc);
#pragma unroll
        for (int mt = 0; mt < 4; ++mt)
#pragma unroll
            for (int nt = 0; nt < 4; ++nt)
                acc[mt][nt] = __builtin_amdgcn_mfma_f32_16x16x32_f16(
                    af[mt], bfr[nt], acc[mt][nt], 0, 0, 0);
    }

#pragma unroll
    for (int mt = 0; mt < 4; ++mt) {
        const int r0 = rb + mt * 16 + quad * 4;
#pragma unroll
        for (int nt = 0; nt < 4; ++nt) {
            const int col = cb + nt * 16 + lm;
            float* Cp = C + (size_t)r0 * VOUT + col;
#pragma unroll
            for (int r = 0; r < 4; ++r)
                Cp[(size_t)r * VOUT] = acc[mt][nt][r];
        }
    }
}

// ---------------------------------------------------------------------------
extern "C" void kernel_launch(void* const* d_in, const int* in_sizes, int n_in,
                              void* d_out, int out_size, void* d_ws, size_t ws_size,
                              hipStream_t stream) {
    (void)in_sizes; (void)n_in; (void)out_size; (void)ws_size;
    const int*   source  = (const int*)  d_in[0];
    const int*   target  = (const int*)  d_in[1];
    const float* src_emb = (const float*)d_in[2];
    const float* tgt_emb = (const float*)d_in[3];
    const float* Wf      = (const float*)d_in[4];
    const float* Uf      = (const float*)d_in[5];
    const float* bf      = (const float*)d_in[6];
    const float* Wb      = (const float*)d_in[7];
    const float* Ub      = (const float*)d_in[8];
    const float* bb      = (const float*)d_in[9];
    const float* W1      = (const float*)d_in[10];
    const float* b1      = (const float*)d_in[11];
    const float* W2      = (const float*)d_in[12];
    const float* b2      = (const float*)d_in[13];
    const float* Vw      = (const float*)d_in[14];
    const float* Vb      = (const float*)d_in[15];
    const float* Wd      = (const float*)d_in[16];
    const float* bd      = (const float*)d_in[17];
    const float* Wfc     = (const float*)d_in[18];
    const float* bfc     = (const float*)d_in[19];
    float* out = (float*)d_out;

    // workspace layout (float offsets)
    float* ws     = (float*)d_ws;
    float* Zf     = ws;                      // 1048576 f (dead after k_scan)
    float* Zb     = Zf + 1048576;            // 1048576 f (dead after k_scan)
    float* enc    = Zb + 1048576;            // 524288 f
    float* hidden = enc + 524288;            // 1024 f
    float* q2     = hidden + 1024;           // 2048 f
    float* scores = q2 + 2048;               // 8192 f
    float* ctx    = scores + 8192;           // 1024 f
    unsigned short* Ah = (unsigned short*)(ctx + 1024);  // 2048*128 fp16
    unsigned short* Bt = (unsigned short*)Zf;            // aliases dead Zf/Zb

    k_embed_gemm<<<1024, 256, 0, stream>>>(source, src_emb, Wf, bf, Wb, bb, Zf, Zb);
    k_scan<<<32, 64, 0, stream>>>(Zf, Zb, Uf, Ub, enc, hidden);
    k_q<<<16, 128, 0, stream>>>(hidden, W1, b1, b2, q2);
    k_score<<<8192, 128, 0, stream>>>(enc, q2, W2, Vw, Vb, scores);
    k_softmax_ctx<<<16, 512, 0, stream>>>(scores, enc, ctx);
    k_cvtB<<<500, 256, 0, stream>>>(Wfc, Bt);   // after k_scan: Zf/Zb dead
    k_dec<<<256, 384, 0, stream>>>(target, tgt_emb, ctx, Wd, bd, Ah);
    k_out_f16<<<dim3(250, 16), 256, 0, stream>>>(Ah, Bt, bfc, out);
}